// Round 11
// baseline (135.843 us; speedup 1.0000x reference)
//
#include <hip/hip_runtime.h>
#include <hip/hip_bf16.h>
#include <stdint.h>

#define DIM 768
#define NP  784
#define NH  12
#define HD  64
#define BATCH 8
#define MROWS (BATCH*NP)   // 6272
#define MPAD 832           // 13*64
#define NCHUNK 32
#define KCH 24             // 768/32
#define L2E 1.4426950408889634f

using bf16x8 = __attribute__((ext_vector_type(8))) short;
using bf16x4 = __attribute__((ext_vector_type(4))) short;
using f32x4  = __attribute__((ext_vector_type(4))) float;

__device__ __forceinline__ short f2bf(float f) {
  union { float f; uint32_t u; } c; c.f = f;
  uint32_t u = c.u;
  u += 0x7FFFu + ((u >> 16) & 1u);   // RNE
  return (short)(u >> 16);
}

__device__ __forceinline__ short bfr(float x) {
  union { __hip_bfloat16 b; short s; } u;
  u.b = __float2bfloat16(x);
  return u.s;
}

__device__ __forceinline__ void gld_lds16(const void* g, void* l) {
  __builtin_amdgcn_global_load_lds((const __attribute__((address_space(1))) uint32_t*)g,
                                   (__attribute__((address_space(3))) uint32_t*)l,
                                   16, 0, 0);
}

// ---------------- prep: x_s -> bf16 ----------------
__global__ __launch_bounds__(256) void cvt_bf16_kernel(const float* __restrict__ src,
                                                       short* __restrict__ dst, int n8) {
  int i = blockIdx.x * 256 + threadIdx.x;
  if (i >= n8) return;
  const float4* s = (const float4*)src;
  float4 a = s[2*i], b = s[2*i+1];
  bf16x8 o;
  o[0]=f2bf(a.x); o[1]=f2bf(a.y); o[2]=f2bf(a.z); o[3]=f2bf(a.w);
  o[4]=f2bf(b.x); o[5]=f2bf(b.y); o[6]=f2bf(b.z); o[7]=f2bf(b.w);
  ((bf16x8*)dst)[i] = o;
}

// ---------------- prep: W[k][n] -> Wt[n][k] bf16 (4 matrices) ----------------
__global__ __launch_bounds__(256) void wtrans_kernel(const float* __restrict__ w0,
                                                     const float* __restrict__ w1,
                                                     const float* __restrict__ w2,
                                                     const float* __restrict__ w3,
                                                     short* __restrict__ dst) {
  __shared__ float tile[32][33];
  const int z = blockIdx.z;
  const float* src = (z==0) ? w0 : (z==1) ? w1 : (z==2) ? w2 : w3;
  short* d = dst + (size_t)z * DIM * DIM;
  const int n0 = blockIdx.x*32, k0 = blockIdx.y*32;
  const int tx = threadIdx.x, ty = threadIdx.y;  // (32,8)
#pragma unroll
  for (int i=0;i<4;i++) tile[ty+i*8][tx] = src[(size_t)(k0+ty+i*8)*DIM + n0+tx];
  __syncthreads();
#pragma unroll
  for (int i=0;i<4;i++) d[(size_t)(n0+ty+i*8)*DIM + k0+tx] = f2bf(tile[tx][ty+i*8]);
}

// ---------------- prep: split-k GEMV partials: part[z][kc][b][d] ----------------
__global__ __launch_bounds__(256) void tvec1_kernel(const float* __restrict__ x_t,
                                                    const float* __restrict__ wq,
                                                    const float* __restrict__ wk,
                                                    const float* __restrict__ wv,
                                                    float* __restrict__ part) {
  const int z = blockIdx.x, kc = blockIdx.y;
  const float* w = (z==0) ? wq : (z==1) ? wk : wv;
  const int d = threadIdx.x;
  __shared__ float xs[BATCH][KCH];
  if (threadIdx.x < BATCH*KCH)
    xs[threadIdx.x / KCH][threadIdx.x % KCH] =
        x_t[(size_t)(threadIdx.x / KCH)*DIM + kc*KCH + threadIdx.x % KCH];
  __syncthreads();
  float a0[BATCH] = {}, a1[BATCH] = {}, a2[BATCH] = {};
#pragma unroll 4
  for (int k = 0; k < KCH; ++k) {
    const float* wr = w + (size_t)(kc*KCH + k)*DIM + d;
    float w0 = wr[0], w1 = wr[256], w2 = wr[512];
#pragma unroll
    for (int b = 0; b < BATCH; ++b) {
      float xv = xs[b][k];
      a0[b] += xv*w0; a1[b] += xv*w1; a2[b] += xv*w2;
    }
  }
#pragma unroll
  for (int b = 0; b < BATCH; ++b) {
    float* p = part + (((size_t)z*NCHUNK + kc)*BATCH + b)*DIM + d;
    p[0] = a0[b]; p[256] = a1[b]; p[512] = a2[b];
  }
}

// ---------------- reduce partials -> t[z][b][d] ----------------
__global__ __launch_bounds__(256) void tvec2_kernel(const float* __restrict__ part,
                                                    float* __restrict__ t) {
  const int i = blockIdx.x*256 + threadIdx.x;   // 3*8*768 = 18432
  if (i >= 3*BATCH*DIM) return;
  const int z = i / (BATCH*DIM), rem = i % (BATCH*DIM);
  float s = 0.f;
#pragma unroll 8
  for (int c = 0; c < NCHUNK; ++c)
    s += part[((size_t)z*NCHUNK + c)*BATCH*DIM + rem];
  t[i] = s;
}

// ---------------- QKV GEMM, 256x256, BK=64, 8 waves, 4-phase spread-stage body ----------------
// m201-style: per phase {ds_read subtile || 4 gld_lds (A at ph0, B at ph1) -> barrier ->
// lgkmcnt(0)+sched_barrier -> setprio -> 16 MFMA -> setprio -> barrier}; vmcnt(0) only at ph3.
// Fully static 2-tile unroll (named buffers). Stage targets only the opposite buffer set.
__global__ __launch_bounds__(512, 1) void qkv256_kernel(const short* __restrict__ A,
                                                        const short* __restrict__ Wt,
                                                        const float* __restrict__ aux,
                                                        short* __restrict__ outq,
                                                        short* __restrict__ outk,
                                                        short* __restrict__ outv) {
  __shared__ short As0[256*64];
  __shared__ short As1[256*64];
  __shared__ short Bs0[256*64];
  __shared__ short Bs1[256*64];
  const int bx = blockIdx.x, by = blockIdx.y;
  const int z = bx / 3;
  const int n0z = (bx - z*3) * 256;
  const short* Bz = Wt + (size_t)z * DIM * DIM;
  const int m0 = by * 256;
  const int tid = threadIdx.x, w = tid >> 6, lane = tid & 63;
  const int wr = w >> 2, wc = w & 3, ln15 = lane & 15, lg = lane >> 4;

  const int lr8 = lane >> 3, c8e = (lane & 7) * 8;
  const int swe = c8e ^ (lr8 << 3);              // elem ^= (row&7)<<3 (pre-swizzled source)
  const short* aS = A  + (size_t)(m0  + w*8 + lr8) * DIM + swe;
  const short* bS = Bz + (size_t)(n0z + w*8 + lr8) * DIM + swe;

#define STGA(DST, KK) { char* d_ = (char*)(DST) + w*1024; \
    gld_lds16(aS + (size_t)0*64*DIM + (KK), d_ + 0*8192); \
    gld_lds16(aS + (size_t)1*64*DIM + (KK), d_ + 1*8192); \
    gld_lds16(aS + (size_t)2*64*DIM + (KK), d_ + 2*8192); \
    gld_lds16(aS + (size_t)3*64*DIM + (KK), d_ + 3*8192); }
#define STGB(DST, KK) { char* d_ = (char*)(DST) + w*1024; \
    gld_lds16(bS + (size_t)0*64*DIM + (KK), d_ + 0*8192); \
    gld_lds16(bS + (size_t)1*64*DIM + (KK), d_ + 1*8192); \
    gld_lds16(bS + (size_t)2*64*DIM + (KK), d_ + 2*8192); \
    gld_lds16(bS + (size_t)3*64*DIM + (KK), d_ + 3*8192); }

#define RDB(BB) { _Pragma("unroll") \
    for (int ni = 0; ni < 4; ++ni) { \
      const int row_ = wc*64 + ni*16 + ln15; \
      bfv0[ni] = *(const bf16x8*)&(BB)[row_*64 + ((lg*8) ^ ((row_ & 7) << 3))]; \
      bfv1[ni] = *(const bf16x8*)&(BB)[row_*64 + ((32 + lg*8) ^ ((row_ & 7) << 3))]; } }

#define RDA(AB, MB) { _Pragma("unroll") \
    for (int c = 0; c < 2; ++c) { \
      const int row_ = wr*128 + ((MB)+c)*16 + ln15; \
      afv0[c] = *(const bf16x8*)&(AB)[row_*64 + ((lg*8) ^ ((row_ & 7) << 3))]; \
      afv1[c] = *(const bf16x8*)&(AB)[row_*64 + ((32 + lg*8) ^ ((row_ & 7) << 3))]; } }

#define MM(MB) { _Pragma("unroll") \
    for (int c = 0; c < 2; ++c) { _Pragma("unroll") \
      for (int ni = 0; ni < 4; ++ni) { \
        acc[(MB)+c][ni] = __builtin_amdgcn_mfma_f32_16x16x32_bf16(afv0[c], bfv0[ni], acc[(MB)+c][ni], 0,0,0); \
        acc[(MB)+c][ni] = __builtin_amdgcn_mfma_f32_16x16x32_bf16(afv1[c], bfv1[ni], acc[(MB)+c][ni], 0,0,0); } } }

#define WAITK  asm volatile("s_waitcnt lgkmcnt(0)" ::: "memory"); __builtin_amdgcn_sched_barrier(0)
#define BAR    __builtin_amdgcn_s_barrier()
#define PRIO1  __builtin_amdgcn_s_setprio(1)
#define PRIO0  __builtin_amdgcn_s_setprio(0)

// One K-tile: 4 phases. Stage next tile's A at ph0, B at ph1 (into opposite buffer set).
// vmcnt(0) before ph3's barrier: next tile's 8 loads (issued ph0/ph1) complete with
// ~2 phases of cover; the barrier publishes completion to all waves.
#define TILE(AB, BB, NA, NB, KK, DOSTG) { \
    RDB(BB); RDA(AB, 0); \
    if (DOSTG) STGA(NA, KK); \
    BAR; WAITK; PRIO1; MM(0); PRIO0; BAR; \
    RDA(AB, 2); \
    if (DOSTG) STGB(NB, KK); \
    BAR; WAITK; PRIO1; MM(2); PRIO0; BAR; \
    RDA(AB, 4); \
    BAR; WAITK; PRIO1; MM(4); PRIO0; BAR; \
    RDA(AB, 6); \
    asm volatile("s_waitcnt vmcnt(0)" ::: "memory"); \
    BAR; WAITK; PRIO1; MM(6); PRIO0; BAR; }

  f32x4 acc[8][4] = {};
  bf16x8 bfv0[4], bfv1[4], afv0[2], afv1[2];

  STGA(As0, 0)
  STGB(Bs0, 0)
  asm volatile("s_waitcnt vmcnt(0)" ::: "memory");
  BAR;

  for (int tp = 0; tp < 6; ++tp) {
    const int k1 = (2*tp + 1) * 64;
    const int k2 = (2*tp + 2) * 64;
    TILE(As0, Bs0, As1, Bs1, k1, true)            // even tile 2tp, stages tile 2tp+1
    TILE(As1, Bs1, As0, Bs0, k2, (tp < 5))        // odd tile 2tp+1, stages 2tp+2
  }

  // epilogue
  const float scl = 0.125f * L2E;
#pragma unroll
  for (int ai = 0; ai < 8; ++ai) {
    const int rb = m0 + wr*128 + (ai>>2)*64 + (ai&3)*16 + lg*4;
    if (z == 2) {
      if (rb < MROWS) {
        const int bb = rb / NP;
        const int m  = rb - bb*NP;          // j-quad never crosses batch (784%4==0)
        const float* tv = aux + ((size_t)2*BATCH + bb) * DIM;
#pragma unroll
        for (int ni = 0; ni < 4; ++ni) {
          const int col = n0z + wc*64 + ni*16 + ln15;
          const int h = col >> 6, d = col & 63;
          const float tb = tv[col];
          bf16x4 ov;
          ov[0] = f2bf(acc[ai][ni][0] + tb);
          ov[1] = f2bf(acc[ai][ni][1] + tb);
          ov[2] = f2bf(acc[ai][ni][2] + tb);
          ov[3] = f2bf(acc[ai][ni][3] + tb);
          *(bf16x4*)&outv[((size_t)(bb*NH + h)*HD + d)*MPAD + m] = ov;
        }
      }
    } else {
#pragma unroll
      for (int j = 0; j < 4; ++j) {
        const int r = rb + j;
        if (r < MROWS) {
          const int bb = r / NP;
          const int m  = r - bb*NP;
          const float* tv = aux + ((size_t)z*BATCH + bb) * DIM;
#pragma unroll
          for (int ni = 0; ni < 4; ++ni) {
            const int col = n0z + wc*64 + ni*16 + ln15;
            if (z == 0) {
              outq[(size_t)r*DIM + col] = f2bf((acc[ai][ni][j] + tv[col]) * scl);
            } else {
              const int h = col >> 6, d = col & 63;
              outk[((size_t)(bb*NH + h)*MPAD + m)*HD + d] = f2bf(acc[ai][ni][j] + tv[col]);
            }
          }
        }
      }
    }
  }
#undef STGA
#undef STGB
#undef RDB
#undef RDA
#undef MM
#undef WAITK
#undef BAR
#undef PRIO1
#undef PRIO0
#undef TILE
}

// ---------------- GEMM 128x128 (proj only): C = A * Bt + bias, f32 out ----------------
template<int MODE>
__global__ __launch_bounds__(256) void gemm_kernel(const short* __restrict__ A,
                                                   const short* __restrict__ Bw,
                                                   const float* __restrict__ aux,
                                                   float* __restrict__ outf) {
  __shared__ short As[128*32];
  __shared__ short Bs[128*32];
  const int bx = blockIdx.x, by = blockIdx.y;
  const short* Bz = Bw;
  const int tid = threadIdx.x, w = tid>>6, lane = tid&63;
  const int wr = w>>1, wc = w&1, ln15 = lane&15, lg = lane>>4;
  const int m0 = by*128, n0 = bx*128;

  f32x4 acc[4][4] = {};

  for (int kt=0; kt<24; ++kt) {
    const int k0 = kt*32;
    __syncthreads();
#pragma unroll
    for (int i=0;i<2;i++) {
      const int inst = w*2 + i;
      const int off  = inst*1024 + lane*16;
      const int row  = off >> 6;
      const int ce   = (off & 63) >> 1;
      gld_lds16(A  + (size_t)(m0+row)*DIM + k0 + ce, (char*)As + (size_t)inst*1024);
      gld_lds16(Bz + (size_t)(n0+row)*DIM + k0 + ce, (char*)Bs + (size_t)inst*1024);
    }
    __syncthreads();
    bf16x8 af[4], bfr_[4];
#pragma unroll
    for (int mi=0;mi<4;mi++) af[mi]   = *(const bf16x8*)&As[(wr*64+mi*16+ln15)*32 + lg*8];
#pragma unroll
    for (int ni=0;ni<4;ni++) bfr_[ni] = *(const bf16x8*)&Bs[(wc*64+ni*16+ln15)*32 + lg*8];
#pragma unroll
    for (int mi=0;mi<4;mi++)
#pragma unroll
      for (int ni=0;ni<4;ni++)
        acc[mi][ni] = __builtin_amdgcn_mfma_f32_16x16x32_bf16(af[mi], bfr_[ni], acc[mi][ni], 0,0,0);
  }

#pragma unroll
  for (int mi=0;mi<4;mi++)
#pragma unroll
    for (int j=0;j<4;j++) {
      const int r = m0 + wr*64 + mi*16 + lg*4 + j;
#pragma unroll
      for (int ni=0;ni<4;ni++) {
        const int gcol = n0 + wc*64 + ni*16 + ln15;
        outf[(size_t)r*DIM + gcol] = acc[mi][ni][j] + aux[gcol];
      }
    }
}

// ---------------- flash attention v7: 4 waves x 32 q-rows/wave (2 groups) ----------------
__global__ __launch_bounds__(256, 3) void attn7_kernel(const short* __restrict__ Qb,
                                                       const short* __restrict__ Kt,
                                                       const short* __restrict__ Vt,
                                                       const float* __restrict__ rpb,
                                                       short* __restrict__ Ob) {
  __shared__ short kt[2][4096];    // K tile [64 m][64 d], byte ^= (row&7)<<4 swizzle
  __shared__ short vt[2][4096];    // V^T tile [64 d][64 m], same swizzle
  __shared__ float4 bias4[112];    // bias4[i] = {be[i], be[i-1], be[i-2], be[i-3]}, log2 domain
  const int hw = blockIdx.x;
  const int lgid = (hw & 7) * 84 + (hw >> 3);
  const int qt = lgid % 7;
  const int bh = lgid / 7;
  const int h = bh % NH, b = bh / NH;
  const int q0 = qt*128, tid = threadIdx.x, w = tid >> 6, lane = tid & 63;
  const int ln15 = lane & 15, lg = lane >> 4;

  if (tid < 112) {
    float4 v;
#pragma unroll
    for (int j = 0; j < 4; ++j) {
      const int i = tid - j - 2;
      float bv = 0.f;
      if (i >= 0 && i < 109)
        bv = rpb[(i/55)*(55*NH) + (i%55)*NH + h] * L2E;
      ((float*)&v)[j] = bv;
    }
    bias4[tid] = v;
  }

  const bool actA = (q0 + w*16) < NP;
  const bool actB = (q0 + 64 + w*16) < NP;
  const int qA = q0 + w*16 + ln15;
  const int qB = qA + 64;
  bf16x8 qfA0 = {}, qfA1 = {}, qfB0 = {}, qfB1 = {};
  if (actA) {
    const short* qp = Qb + ((size_t)(b*NP) + qA)*DIM + h*HD + lg*8;
    qfA0 = *(const bf16x8*)qp;
    qfA1 = *(const bf16x8*)(qp + 32);
  }
  if (actB) {
    const short* qp = Qb + ((size_t)(b*NP) + qB)*DIM + h*HD + lg*8;
    qfB0 = *(const bf16x8*)qp;
    qfB1 = *(const bf16x8*)(qp + 32);
  }
  const int qs56A = qA/28 + qA%28 + 56;
  const int qs56B = qB/28 + qB%28 + 56;

  const int lr = lane >> 3, lc = lane & 7;
  const int swe = (lc ^ lr) << 3;
  const size_t bhs = (size_t)bh;
  const short* kp0 = Kt + (bhs*MPAD + (size_t)(w*16 + lr))*HD + swe;
  const short* kp1 = kp0 + 8*HD;
  const short* vp0 = Vt + (bhs*HD + (size_t)(w*16 + lr))*MPAD + swe;
  const short* vp1 = vp0 + 8*MPAD;

#define STAGE4(BUF) { \
    gld_lds16(kp0, (char*)kt[BUF] + w*2048); \
    gld_lds16(kp1, (char*)kt[BUF] + w*2048 + 1024); \
    gld_lds16(vp0, (char*)vt[BUF] + w*2048); \
    gld_lds16(vp1, (char*)vt[BUF] + w*2048 + 1024); \
    kp0 += 64*HD; kp1 += 64*HD; vp0 += 64; vp1 += 64; }

  float lA = 0.f, lB = 0.f;
  f32x4 oA0={}, oA1={}, oA2={}, oA3={};
  f32x4 oB0={}, oB1={}, oB2={}, oB3={};

  STAGE4(0)

  for (int t = 0; t < 13; ++t) {
    const int cur = t & 1;
    const int m0 = t * 64;
    __syncthreads();
    if (t < 12) STAGE4(cur^1)
    if (actA || actB) {
      const char* kb = (const char*)kt[cur];
      const int sw = (ln15 & 7) << 4;
      f32x4 sA[4], sB[4];
#pragma unroll
      for (int mc = 0; mc < 4; ++mc) {
        const int rb = (mc*16 + ln15) * 128;
        bf16x8 kf0 = *(const bf16x8*)(kb + rb + ((lg*16) ^ sw));
        bf16x8 kf1 = *(const bf16x8*)(kb + rb + ((lg*16 + 64) ^ sw));
        f32x4 a = {};
        a = __builtin_amdgcn_mfma_f32_16x16x32_bf16(kf0, qfA0, a, 0,0,0);
        a = __builtin_amdgcn_mfma_f32_16x16x32_bf16(kf1, qfA1, a, 0,0,0);
        sA[mc] = a;
        f32x4 c = {};
        c = __builtin_amdgcn_mfma_f32_16x16x32_bf16(kf0, qfB0, c, 0,0,0);
        c = __builtin_amdgcn_mfma_f32_16x16x32_bf16(kf1, qfB1, c, 0,0,0);
        sB[mc] = c;
      }
#pragma unroll
      for (int mc = 0; mc < 4; ++mc) {
        const int mb = m0 + mc*16 + lg*4;
        const int a28 = (mb * 2341) >> 16;          // mb/28 (exact for mb<5400)
        const int rel = 27*a28 - mb;
        const float4 bA = bias4[qs56A + rel];
        const float4 bB = bias4[qs56B + rel];
        sA[mc][0] += bA.x; sA[mc][1] += bA.y; sA[mc][2] += bA.z; sA[mc][3] += bA.w;
        sB[mc][0] += bB.x; sB[mc][1] += bB.y; sB[mc][2] += bB.z; sB[mc][3] += bB.w;
      }
      if (m0 + 64 > NP) {
#pragma unroll
        for (int mc = 0; mc < 4; ++mc)
#pragma unroll
          for (int j = 0; j < 4; ++j)
            if (m0 + mc*16 + lg*4 + j >= NP) { sA[mc][j] = -1e30f; sB[mc][j] = -1e30f; }
      }
      float tsA = 0.f, tsB = 0.f;
      bf16x4 pbA[4], pbB[4];
#pragma unroll
      for (int mc = 0; mc < 4; ++mc) {
        float a0 = exp2f(sA[mc][0]), a1 = exp2f(sA[mc][1]);
        float a2 = exp2f(sA[mc][2]), a3 = exp2f(sA[mc][3]);
        float b0 = exp2f(sB[mc][0]), b1 = exp2f(sB[mc][1]);
        float b2 = exp2f(sB[mc][2]), b3 = exp2f(sB[mc][3]);
        tsA += (a0+a1)+(a2+a3);
        tsB += (b0+b1)+(b2+b3);
        pbA[mc][0]=bfr(a0); pbA[mc][1]=bfr(a1); pbA[mc][2]=bfr(a2); pbA[mc][3]=bfr(a3);
        pbB[mc][0]=bfr(b0); pbB[mc][1]=bfr(b1); pbB[mc][2]=bfr(b2); pbB[mc][3]=bfr(b3);
      }
      lA += tsA; lB += tsB;
      const char* vb = (const char*)vt[cur];
#pragma unroll
      for (int mc = 0; mc < 4; ++mc) {
        const int ib = (mc*32 + lg*8) ^ sw;
        bf16x4 vf0 = *(const bf16x4*)(vb + (0*16+ln15)*128 + ib);
        bf16x4 vf1 = *(const bf16x4*)(vb + (1*16+ln15)*128 + ib);
        bf16x4 vf2 = *(const bf16x4*)(vb + (2*16+ln15)*128 + ib);
        bf16x4 vf3 = *(const bf16x4*)(vb + (3*16+ln15)*128 + ib);
        oA0 = __builtin_amdgcn_mfma_f32_16x16x16bf16_1k(vf0, pbA[mc], oA0, 0,0,0);
        oA1 = __builtin_amdgcn_mfma_f32_16x16x16bf16_1k(vf1, pbA[mc], oA1, 0,0,0);
        oA2 = __builtin_amdgcn_mfma_f32_16x16x16bf16_1k(vf2, pbA[mc], oA2, 0,0,0);
        oA3 = __builtin_amdgcn_mfma_f32_16x16x16bf16_1k(vf3, pbA[mc], oA3, 0,0,0);
        oB0 = __builtin_amdgcn_mfma_f32_16x16x16bf16_1k(vf0, pbB[mc], oB0, 0,0,0);
        oB1 = __builtin_amdgcn_mfma_f32_16x16x16bf16_1k(vf1, pbB[mc], oB1, 0,0,0);
        oB2 = __builtin_amdgcn_mfma_f32_16x16x16bf16_1k(vf2, pbB[mc], oB2, 0,0,0);
        oB3 = __builtin_amdgcn_mfma_f32_16x16x16bf16_1k(vf3, pbB[mc], oB3, 0,0,0);
      }
    }
  }
#undef STAGE4

  if (actA) {
    float l = lA;
    l += __shfl_xor(l, 16);
    l += __shfl_xor(l, 32);
    const float inv = 1.0f / l;
    short* op = Ob + ((size_t)(b*NP) + qA)*DIM + h*HD + lg*4;
    bf16x4 ov;
    ov[0]=bfr(oA0[0]*inv); ov[1]=bfr(oA0[1]*inv); ov[2]=bfr(oA0[2]*inv); ov[3]=bfr(oA0[3]*inv);
    *(bf16x4*)(op + 0*16) = ov;
    ov[0]=bfr(oA1[0]*inv); ov[1]=bfr(oA1[1]*inv); ov[2]=bfr(oA1[2]*inv); ov[3]=bfr(oA1[3]*inv);
    *(bf16x4*)(op + 1*16) = ov;
    ov[0]=bfr(oA2[0]*inv); ov[1]=bfr(oA2[1]*inv); ov[2]=bfr(oA2[2]*inv); ov[3]=bfr(oA2[3]*inv);
    *(bf16x4*)(op + 2*16) = ov;
    ov[0]=bfr(oA3[0]*inv); ov[1]=bfr(oA3[1]*inv); ov[2]=bfr(oA3[2]*inv); ov[3]=bfr(oA3[3]*inv);
    *(bf16x4*)(op + 3*16) = ov;
  }
  if (actB) {
    float l = lB;
    l += __shfl_xor(l, 16);
    l += __shfl_xor(l, 32);
    const float inv = 1.0f / l;
    short* op = Ob + ((size_t)(b*NP) + qB)*DIM + h*HD + lg*4;
    bf16x4 ov;
    ov[0]=bfr(oB0[0]*inv); ov[1]=bfr(oB0[1]*inv); ov[2]=bfr(oB0[2]*inv); ov[3]=bfr(oB0[3]*inv);
    *(bf16x4*)(op + 0*16) = ov;
    ov[0]=bfr(oB1[0]*inv); ov[1]=bfr(oB1[1]*inv); ov[2]=bfr(oB1[2]*inv); ov[3]=bfr(oB1[3]*inv);
    *(bf16x4*)(op + 1*16) = ov;
    ov[0]=bfr(oB2[0]*inv); ov[1]=bfr(oB2[1]*inv); ov[2]=bfr(oB2[2]*inv); ov[3]=bfr(oB2[3]*inv);
    *(bf16x4*)(op + 2*16) = ov;
    ov[0]=bfr(oB3[0]*inv); ov[1]=bfr(oB3[1]*inv); ov[2]=bfr(oB3[2]*inv); ov[3]=bfr(oB3[3]*inv);
    *(bf16x4*)(op + 3*16) = ov;
  }
}

extern "C" void kernel_launch(void* const* d_in, const int* in_sizes, int n_in,
                              void* d_out, int out_size, void* d_ws, size_t ws_size,
                              hipStream_t stream) {
  const float* x_s = (const float*)d_in[0];
  const float* x_t = (const float*)d_in[1];
  const float* Wqs = (const float*)d_in[2];
  const float* Wqt = (const float*)d_in[3];
  const float* Wks = (const float*)d_in[4];
  const float* Wkt = (const float*)d_in[5];
  const float* Wvs = (const float*)d_in[6];
  const float* Wvt = (const float*)d_in[7];
  const float* rpb = (const float*)d_in[8];
  const float* pw  = (const float*)d_in[9];
  const float* pb  = (const float*)d_in[10];
  float* out = (float*)d_out;

  char* ws = (char*)d_ws;
  size_t off = 0;
  float* t_part = (float*)(ws + off); off += (size_t)3*NCHUNK*BATCH*DIM*4;
  float* t_vec  = (float*)(ws + off); off += (size_t)3*BATCH*DIM*4;
  short* Wt     = (short*)(ws + off); off += (size_t)4*DIM*DIM*2;
  short* Qb     = (short*)(ws + off); off += (size_t)MROWS*DIM*2;
  short* Ob     = (short*)(ws + off); off += (size_t)MROWS*DIM*2;
  short* Xb     = (short*)(ws + off); off += (size_t)(MROWS+256)*DIM*2;  // +256 pad rows (M-tail)
  short* Kt     = (short*)(ws + off); off += (size_t)BATCH*NH*MPAD*HD*2;
  short* Vt     = (short*)(ws + off); off += (size_t)BATCH*NH*MPAD*HD*2;
  // total ~58 MB

  cvt_bf16_kernel<<<2352, 256, 0, stream>>>(x_s, Xb, MROWS*DIM/8);
  wtrans_kernel<<<dim3(24,24,4), dim3(32,8), 0, stream>>>(Wqs, Wks, Wvs, pw, Wt);
  tvec1_kernel<<<dim3(3,NCHUNK), 256, 0, stream>>>(x_t, Wqt, Wkt, Wvt, t_part);
  tvec2_kernel<<<72, 256, 0, stream>>>(t_part, t_vec);
  qkv256_kernel<<<dim3(9,25), 512, 0, stream>>>(Xb, Wt, t_vec, Qb, Kt, Vt);
  attn7_kernel<<<672, 256, 0, stream>>>(Qb, Kt, Vt, rpb, Ob);
  gemm_kernel<1><<<dim3(6,49,1), 256, 0, stream>>>(Ob, Wt + (size_t)3*DIM*DIM, pb, out);
}

// Round 12
// 125.974 us; speedup vs baseline: 1.0783x; 1.0783x over previous
//
#include <hip/hip_runtime.h>
#include <hip/hip_bf16.h>
#include <stdint.h>

#define DIM 768
#define NP  784
#define NH  12
#define HD  64
#define BATCH 8
#define MROWS (BATCH*NP)   // 6272
#define MPAD 832           // 13*64
#define NCHUNK 32
#define KCH 24             // 768/32
#define L2E 1.4426950408889634f

using bf16x8 = __attribute__((ext_vector_type(8))) short;
using bf16x4 = __attribute__((ext_vector_type(4))) short;
using f32x4  = __attribute__((ext_vector_type(4))) float;

__device__ __forceinline__ short f2bf(float f) {
  union { float f; uint32_t u; } c; c.f = f;
  uint32_t u = c.u;
  u += 0x7FFFu + ((u >> 16) & 1u);   // RNE
  return (short)(u >> 16);
}

__device__ __forceinline__ short bfr(float x) {
  union { __hip_bfloat16 b; short s; } u;
  u.b = __float2bfloat16(x);
  return u.s;
}

__device__ __forceinline__ void gld_lds16(const void* g, void* l) {
  __builtin_amdgcn_global_load_lds((const __attribute__((address_space(1))) uint32_t*)g,
                                   (__attribute__((address_space(3))) uint32_t*)l,
                                   16, 0, 0);
}

// ---------------- fused prep: cvt(x_s->bf16) || wtrans(4 matrices) || tvec1 partials ----------
// blocks [0,2352): cvt; [2352,4656): wtrans; [4656,4752): tvec1. Branch is block-uniform.
__global__ __launch_bounds__(256) void prep_kernel(const float* __restrict__ x_s,
                                                   const float* __restrict__ x_t,
                                                   const float* __restrict__ Wqs,
                                                   const float* __restrict__ Wqt,
                                                   const float* __restrict__ Wks,
                                                   const float* __restrict__ Wkt,
                                                   const float* __restrict__ Wvs,
                                                   const float* __restrict__ Wvt,
                                                   const float* __restrict__ pw,
                                                   short* __restrict__ Xb,
                                                   short* __restrict__ Wt,
                                                   float* __restrict__ part) {
  __shared__ float tile[32][33];
  __shared__ float xs[BATCH][KCH];
  const int bid = blockIdx.x, tid = threadIdx.x;

  if (bid < 2352) {
    // ---- cvt: x_s -> bf16, 8 elems/thread (2352*256*8 = 4816896 = MROWS*DIM exactly)
    const int i = bid * 256 + tid;
    const float4* s = (const float4*)x_s;
    float4 a = s[2*i], b = s[2*i+1];
    bf16x8 o;
    o[0]=f2bf(a.x); o[1]=f2bf(a.y); o[2]=f2bf(a.z); o[3]=f2bf(a.w);
    o[4]=f2bf(b.x); o[5]=f2bf(b.y); o[6]=f2bf(b.z); o[7]=f2bf(b.w);
    ((bf16x8*)Xb)[i] = o;
  } else if (bid < 4656) {
    // ---- wtrans: W[k][n] -> Wt[n][k] bf16 (z: 0=Wqs 1=Wks 2=Wvs 3=proj)
    int r = bid - 2352;
    const int z = r / 576; r -= z * 576;
    const int bxx = r % 24, byy = r / 24;
    const float* src = (z==0) ? Wqs : (z==1) ? Wks : (z==2) ? Wvs : pw;
    short* d = Wt + (size_t)z * DIM * DIM;
    const int n0 = bxx*32, k0 = byy*32;
    const int tx = tid & 31, ty = tid >> 5;   // (32,8)
#pragma unroll
    for (int i=0;i<4;i++) tile[ty+i*8][tx] = src[(size_t)(k0+ty+i*8)*DIM + n0+tx];
    __syncthreads();
#pragma unroll
    for (int i=0;i<4;i++) d[(size_t)(n0+ty+i*8)*DIM + k0+tx] = f2bf(tile[tx][ty+i*8]);
  } else {
    // ---- tvec1: split-k GEMV partials part[z][kc][b][d]
    int r = bid - 4656;
    const int z = r >> 5, kc = r & 31;
    const float* w = (z==0) ? Wqt : (z==1) ? Wkt : Wvt;
    const int d = tid;
    if (tid < BATCH*KCH)
      xs[tid / KCH][tid % KCH] = x_t[(size_t)(tid / KCH)*DIM + kc*KCH + tid % KCH];
    __syncthreads();
    float a0[BATCH] = {}, a1[BATCH] = {}, a2[BATCH] = {};
#pragma unroll 4
    for (int k = 0; k < KCH; ++k) {
      const float* wr = w + (size_t)(kc*KCH + k)*DIM + d;
      float w0 = wr[0], w1 = wr[256], w2 = wr[512];
#pragma unroll
      for (int b = 0; b < BATCH; ++b) {
        float xv = xs[b][k];
        a0[b] += xv*w0; a1[b] += xv*w1; a2[b] += xv*w2;
      }
    }
#pragma unroll
    for (int b = 0; b < BATCH; ++b) {
      float* p = part + (((size_t)z*NCHUNK + kc)*BATCH + b)*DIM + d;
      p[0] = a0[b]; p[256] = a1[b]; p[512] = a2[b];
    }
  }
}

// ---------------- reduce partials -> t[z][b][d] ----------------
__global__ __launch_bounds__(256) void tvec2_kernel(const float* __restrict__ part,
                                                    float* __restrict__ t) {
  const int i = blockIdx.x*256 + threadIdx.x;   // 3*8*768 = 18432
  if (i >= 3*BATCH*DIM) return;
  const int z = i / (BATCH*DIM), rem = i % (BATCH*DIM);
  float s = 0.f;
#pragma unroll 8
  for (int c = 0; c < NCHUNK; ++c)
    s += part[((size_t)z*NCHUNK + c)*BATCH*DIM + rem];
  t[i] = s;
}

// ---------------- QKV GEMM, 256x256, BK=64, 8 waves, named double buffers (r9, 51.4us) ----
__global__ __launch_bounds__(512, 1) void qkv256_kernel(const short* __restrict__ A,
                                                        const short* __restrict__ Wt,
                                                        const float* __restrict__ aux,
                                                        short* __restrict__ outq,
                                                        short* __restrict__ outk,
                                                        short* __restrict__ outv) {
  __shared__ short As0[256*64];
  __shared__ short As1[256*64];
  __shared__ short Bs0[256*64];
  __shared__ short Bs1[256*64];
  const int bx = blockIdx.x, by = blockIdx.y;
  const int z = bx / 3;
  const int n0z = (bx - z*3) * 256;
  const short* Bz = Wt + (size_t)z * DIM * DIM;
  const int m0 = by * 256;
  const int tid = threadIdx.x, w = tid >> 6, lane = tid & 63;
  const int wr = w >> 2, wc = w & 3, ln15 = lane & 15, lg = lane >> 4;

  const int lr8 = lane >> 3, c8e = (lane & 7) * 8;
  const int swe = c8e ^ (lr8 << 3);              // elem ^= (row&7)<<3 (pre-swizzled source)
  const short* aS = A  + (size_t)(m0  + w*8 + lr8) * DIM + swe;
  const short* bS = Bz + (size_t)(n0z + w*8 + lr8) * DIM + swe;

#define STG2(DA, DB, TT) { \
    char* da_ = (char*)(DA) + w*1024; \
    char* db_ = (char*)(DB) + w*1024; \
    const int kk_ = (TT)*64; \
    gld_lds16(aS + (size_t)0*64*DIM + kk_, da_ + 0*8192); \
    gld_lds16(bS + (size_t)0*64*DIM + kk_, db_ + 0*8192); \
    gld_lds16(aS + (size_t)1*64*DIM + kk_, da_ + 1*8192); \
    gld_lds16(bS + (size_t)1*64*DIM + kk_, db_ + 1*8192); \
    gld_lds16(aS + (size_t)2*64*DIM + kk_, da_ + 2*8192); \
    gld_lds16(bS + (size_t)2*64*DIM + kk_, db_ + 2*8192); \
    gld_lds16(aS + (size_t)3*64*DIM + kk_, da_ + 3*8192); \
    gld_lds16(bS + (size_t)3*64*DIM + kk_, db_ + 3*8192); }

#define QBODY(AB, BB) { \
    _Pragma("unroll") \
    for (int ks = 0; ks < 2; ++ks) { \
      bf16x8 bfv[4]; \
      _Pragma("unroll") \
      for (int ni = 0; ni < 4; ++ni) { \
        const int row_ = wc*64 + ni*16 + ln15; \
        bfv[ni] = *(const bf16x8*)&(BB)[row_*64 + ((ks*32 + lg*8) ^ ((row_ & 7) << 3))]; \
      } \
      _Pragma("unroll") \
      for (int mi = 0; mi < 8; ++mi) { \
        const int row_ = wr*128 + mi*16 + ln15; \
        bf16x8 afv = *(const bf16x8*)&(AB)[row_*64 + ((ks*32 + lg*8) ^ ((row_ & 7) << 3))]; \
        _Pragma("unroll") \
        for (int ni = 0; ni < 4; ++ni) \
          acc[mi][ni] = __builtin_amdgcn_mfma_f32_16x16x32_bf16(afv, bfv[ni], acc[mi][ni], 0,0,0); \
      } \
    } }

  f32x4 acc[8][4] = {};

  STG2(As0, Bs0, 0)
  STG2(As1, Bs1, 1)

  for (int tt = 0; tt < 5; ++tt) {       // tiles 0..9 (stage tiles 2..11)
    const int t2 = tt*2;
    asm volatile("s_waitcnt vmcnt(8)" ::: "memory");
    __builtin_amdgcn_s_barrier();
    QBODY(As0, Bs0)
    __builtin_amdgcn_s_barrier();
    STG2(As0, Bs0, t2+2)
    asm volatile("s_waitcnt vmcnt(8)" ::: "memory");
    __builtin_amdgcn_s_barrier();
    QBODY(As1, Bs1)
    __builtin_amdgcn_s_barrier();
    STG2(As1, Bs1, t2+3)
  }
  // tile 10
  asm volatile("s_waitcnt vmcnt(8)" ::: "memory");
  __builtin_amdgcn_s_barrier();
  QBODY(As0, Bs0)
  __builtin_amdgcn_s_barrier();
  // tile 11
  asm volatile("s_waitcnt vmcnt(0)" ::: "memory");
  __builtin_amdgcn_s_barrier();
  QBODY(As1, Bs1)

  // epilogue
  const float scl = 0.125f * L2E;
#pragma unroll
  for (int ai = 0; ai < 8; ++ai) {
    const int rb = m0 + wr*128 + (ai>>2)*64 + (ai&3)*16 + lg*4;
    if (z == 2) {
      if (rb < MROWS) {
        const int bb = rb / NP;
        const int m  = rb - bb*NP;          // j-quad never crosses batch (784%4==0)
        const float* tv = aux + ((size_t)2*BATCH + bb) * DIM;
#pragma unroll
        for (int ni = 0; ni < 4; ++ni) {
          const int col = n0z + wc*64 + ni*16 + ln15;
          const int h = col >> 6, d = col & 63;
          const float tb = tv[col];
          bf16x4 ov;
          ov[0] = f2bf(acc[ai][ni][0] + tb);
          ov[1] = f2bf(acc[ai][ni][1] + tb);
          ov[2] = f2bf(acc[ai][ni][2] + tb);
          ov[3] = f2bf(acc[ai][ni][3] + tb);
          *(bf16x4*)&outv[((size_t)(bb*NH + h)*HD + d)*MPAD + m] = ov;
        }
      }
    } else {
#pragma unroll
      for (int j = 0; j < 4; ++j) {
        const int r = rb + j;
        if (r < MROWS) {
          const int bb = r / NP;
          const int m  = r - bb*NP;
          const float* tv = aux + ((size_t)z*BATCH + bb) * DIM;
#pragma unroll
          for (int ni = 0; ni < 4; ++ni) {
            const int col = n0z + wc*64 + ni*16 + ln15;
            if (z == 0) {
              outq[(size_t)r*DIM + col] = f2bf((acc[ai][ni][j] + tv[col]) * scl);
            } else {
              const int h = col >> 6, d = col & 63;
              outk[((size_t)(bb*NH + h)*MPAD + m)*HD + d] = f2bf(acc[ai][ni][j] + tv[col]);
            }
          }
        }
      }
    }
  }
#undef STG2
#undef QBODY
}

// ---------------- GEMM 128x128 (proj only): C = A * Bt + bias, f32 out ----------------
template<int MODE>
__global__ __launch_bounds__(256) void gemm_kernel(const short* __restrict__ A,
                                                   const short* __restrict__ Bw,
                                                   const float* __restrict__ aux,
                                                   float* __restrict__ outf) {
  __shared__ short As[128*32];
  __shared__ short Bs[128*32];
  const int bx = blockIdx.x, by = blockIdx.y;
  const short* Bz = Bw;
  const int tid = threadIdx.x, w = tid>>6, lane = tid&63;
  const int wr = w>>1, wc = w&1, ln15 = lane&15, lg = lane>>4;
  const int m0 = by*128, n0 = bx*128;

  f32x4 acc[4][4] = {};

  for (int kt=0; kt<24; ++kt) {
    const int k0 = kt*32;
    __syncthreads();
#pragma unroll
    for (int i=0;i<2;i++) {
      const int inst = w*2 + i;
      const int off  = inst*1024 + lane*16;
      const int row  = off >> 6;
      const int ce   = (off & 63) >> 1;
      gld_lds16(A  + (size_t)(m0+row)*DIM + k0 + ce, (char*)As + (size_t)inst*1024);
      gld_lds16(Bz + (size_t)(n0+row)*DIM + k0 + ce, (char*)Bs + (size_t)inst*1024);
    }
    __syncthreads();
    bf16x8 af[4], bfr_[4];
#pragma unroll
    for (int mi=0;mi<4;mi++) af[mi]   = *(const bf16x8*)&As[(wr*64+mi*16+ln15)*32 + lg*8];
#pragma unroll
    for (int ni=0;ni<4;ni++) bfr_[ni] = *(const bf16x8*)&Bs[(wc*64+ni*16+ln15)*32 + lg*8];
#pragma unroll
    for (int mi=0;mi<4;mi++)
#pragma unroll
      for (int ni=0;ni<4;ni++)
        acc[mi][ni] = __builtin_amdgcn_mfma_f32_16x16x32_bf16(af[mi], bfr_[ni], acc[mi][ni], 0,0,0);
  }

#pragma unroll
  for (int mi=0;mi<4;mi++)
#pragma unroll
    for (int j=0;j<4;j++) {
      const int r = m0 + wr*64 + mi*16 + lg*4 + j;
#pragma unroll
      for (int ni=0;ni<4;ni++) {
        const int gcol = n0 + wc*64 + ni*16 + ln15;
        outf[(size_t)r*DIM + gcol] = acc[mi][ni][j] + aux[gcol];
      }
    }
}

// ---------------- flash attention v7: 4 waves x 32 q-rows/wave (2 groups) ----------------
__global__ __launch_bounds__(256, 3) void attn7_kernel(const short* __restrict__ Qb,
                                                       const short* __restrict__ Kt,
                                                       const short* __restrict__ Vt,
                                                       const float* __restrict__ rpb,
                                                       short* __restrict__ Ob) {
  __shared__ short kt[2][4096];    // K tile [64 m][64 d], byte ^= (row&7)<<4 swizzle
  __shared__ short vt[2][4096];    // V^T tile [64 d][64 m], same swizzle
  __shared__ float4 bias4[112];    // bias4[i] = {be[i], be[i-1], be[i-2], be[i-3]}, log2 domain
  const int hw = blockIdx.x;
  const int lgid = (hw & 7) * 84 + (hw >> 3);
  const int qt = lgid % 7;
  const int bh = lgid / 7;
  const int h = bh % NH, b = bh / NH;
  const int q0 = qt*128, tid = threadIdx.x, w = tid >> 6, lane = tid & 63;
  const int ln15 = lane & 15, lg = lane >> 4;

  if (tid < 112) {
    float4 v;
#pragma unroll
    for (int j = 0; j < 4; ++j) {
      const int i = tid - j - 2;
      float bv = 0.f;
      if (i >= 0 && i < 109)
        bv = rpb[(i/55)*(55*NH) + (i%55)*NH + h] * L2E;
      ((float*)&v)[j] = bv;
    }
    bias4[tid] = v;
  }

  const bool actA = (q0 + w*16) < NP;
  const bool actB = (q0 + 64 + w*16) < NP;
  const int qA = q0 + w*16 + ln15;
  const int qB = qA + 64;
  bf16x8 qfA0 = {}, qfA1 = {}, qfB0 = {}, qfB1 = {};
  if (actA) {
    const short* qp = Qb + ((size_t)(b*NP) + qA)*DIM + h*HD + lg*8;
    qfA0 = *(const bf16x8*)qp;
    qfA1 = *(const bf16x8*)(qp + 32);
  }
  if (actB) {
    const short* qp = Qb + ((size_t)(b*NP) + qB)*DIM + h*HD + lg*8;
    qfB0 = *(const bf16x8*)qp;
    qfB1 = *(const bf16x8*)(qp + 32);
  }
  const int qs56A = qA/28 + qA%28 + 56;
  const int qs56B = qB/28 + qB%28 + 56;

  const int lr = lane >> 3, lc = lane & 7;
  const int swe = (lc ^ lr) << 3;
  const size_t bhs = (size_t)bh;
  const short* kp0 = Kt + (bhs*MPAD + (size_t)(w*16 + lr))*HD + swe;
  const short* kp1 = kp0 + 8*HD;
  const short* vp0 = Vt + (bhs*HD + (size_t)(w*16 + lr))*MPAD + swe;
  const short* vp1 = vp0 + 8*MPAD;

#define STAGE4(BUF) { \
    gld_lds16(kp0, (char*)kt[BUF] + w*2048); \
    gld_lds16(kp1, (char*)kt[BUF] + w*2048 + 1024); \
    gld_lds16(vp0, (char*)vt[BUF] + w*2048); \
    gld_lds16(vp1, (char*)vt[BUF] + w*2048 + 1024); \
    kp0 += 64*HD; kp1 += 64*HD; vp0 += 64; vp1 += 64; }

  float lA = 0.f, lB = 0.f;
  f32x4 oA0={}, oA1={}, oA2={}, oA3={};
  f32x4 oB0={}, oB1={}, oB2={}, oB3={};

  STAGE4(0)

  for (int t = 0; t < 13; ++t) {
    const int cur = t & 1;
    const int m0 = t * 64;
    __syncthreads();
    if (t < 12) STAGE4(cur^1)
    if (actA || actB) {
      const char* kb = (const char*)kt[cur];
      const int sw = (ln15 & 7) << 4;
      f32x4 sA[4], sB[4];
#pragma unroll
      for (int mc = 0; mc < 4; ++mc) {
        const int rb = (mc*16 + ln15) * 128;
        bf16x8 kf0 = *(const bf16x8*)(kb + rb + ((lg*16) ^ sw));
        bf16x8 kf1 = *(const bf16x8*)(kb + rb + ((lg*16 + 64) ^ sw));
        f32x4 a = {};
        a = __builtin_amdgcn_mfma_f32_16x16x32_bf16(kf0, qfA0, a, 0,0,0);
        a = __builtin_amdgcn_mfma_f32_16x16x32_bf16(kf1, qfA1, a, 0,0,0);
        sA[mc] = a;
        f32x4 c = {};
        c = __builtin_amdgcn_mfma_f32_16x16x32_bf16(kf0, qfB0, c, 0,0,0);
        c = __builtin_amdgcn_mfma_f32_16x16x32_bf16(kf1, qfB1, c, 0,0,0);
        sB[mc] = c;
      }
#pragma unroll
      for (int mc = 0; mc < 4; ++mc) {
        const int mb = m0 + mc*16 + lg*4;
        const int a28 = (mb * 2341) >> 16;          // mb/28 (exact for mb<5400)
        const int rel = 27*a28 - mb;
        const float4 bA = bias4[qs56A + rel];
        const float4 bB = bias4[qs56B + rel];
        sA[mc][0] += bA.x; sA[mc][1] += bA.y; sA[mc][2] += bA.z; sA[mc][3] += bA.w;
        sB[mc][0] += bB.x; sB[mc][1] += bB.y; sB[mc][2] += bB.z; sB[mc][3] += bB.w;
      }
      if (m0 + 64 > NP) {
#pragma unroll
        for (int mc = 0; mc < 4; ++mc)
#pragma unroll
          for (int j = 0; j < 4; ++j)
            if (m0 + mc*16 + lg*4 + j >= NP) { sA[mc][j] = -1e30f; sB[mc][j] = -1e30f; }
      }
      float tsA = 0.f, tsB = 0.f;
      bf16x4 pbA[4], pbB[4];
#pragma unroll
      for (int mc = 0; mc < 4; ++mc) {
        float a0 = exp2f(sA[mc][0]), a1 = exp2f(sA[mc][1]);
        float a2 = exp2f(sA[mc][2]), a3 = exp2f(sA[mc][3]);
        float b0 = exp2f(sB[mc][0]), b1 = exp2f(sB[mc][1]);
        float b2 = exp2f(sB[mc][2]), b3 = exp2f(sB[mc][3]);
        tsA += (a0+a1)+(a2+a3);
        tsB += (b0+b1)+(b2+b3);
        pbA[mc][0]=bfr(a0); pbA[mc][1]=bfr(a1); pbA[mc][2]=bfr(a2); pbA[mc][3]=bfr(a3);
        pbB[mc][0]=bfr(b0); pbB[mc][1]=bfr(b1); pbB[mc][2]=bfr(b2); pbB[mc][3]=bfr(b3);
      }
      lA += tsA; lB += tsB;
      const char* vb = (const char*)vt[cur];
#pragma unroll
      for (int mc = 0; mc < 4; ++mc) {
        const int ib = (mc*32 + lg*8) ^ sw;
        bf16x4 vf0 = *(const bf16x4*)(vb + (0*16+ln15)*128 + ib);
        bf16x4 vf1 = *(const bf16x4*)(vb + (1*16+ln15)*128 + ib);
        bf16x4 vf2 = *(const bf16x4*)(vb + (2*16+ln15)*128 + ib);
        bf16x4 vf3 = *(const bf16x4*)(vb + (3*16+ln15)*128 + ib);
        oA0 = __builtin_amdgcn_mfma_f32_16x16x16bf16_1k(vf0, pbA[mc], oA0, 0,0,0);
        oA1 = __builtin_amdgcn_mfma_f32_16x16x16bf16_1k(vf1, pbA[mc], oA1, 0,0,0);
        oA2 = __builtin_amdgcn_mfma_f32_16x16x16bf16_1k(vf2, pbA[mc], oA2, 0,0,0);
        oA3 = __builtin_amdgcn_mfma_f32_16x16x16bf16_1k(vf3, pbA[mc], oA3, 0,0,0);
        oB0 = __builtin_amdgcn_mfma_f32_16x16x16bf16_1k(vf0, pbB[mc], oB0, 0,0,0);
        oB1 = __builtin_amdgcn_mfma_f32_16x16x16bf16_1k(vf1, pbB[mc], oB1, 0,0,0);
        oB2 = __builtin_amdgcn_mfma_f32_16x16x16bf16_1k(vf2, pbB[mc], oB2, 0,0,0);
        oB3 = __builtin_amdgcn_mfma_f32_16x16x16bf16_1k(vf3, pbB[mc], oB3, 0,0,0);
      }
    }
  }
#undef STAGE4

  if (actA) {
    float l = lA;
    l += __shfl_xor(l, 16);
    l += __shfl_xor(l, 32);
    const float inv = 1.0f / l;
    short* op = Ob + ((size_t)(b*NP) + qA)*DIM + h*HD + lg*4;
    bf16x4 ov;
    ov[0]=bfr(oA0[0]*inv); ov[1]=bfr(oA0[1]*inv); ov[2]=bfr(oA0[2]*inv); ov[3]=bfr(oA0[3]*inv);
    *(bf16x4*)(op + 0*16) = ov;
    ov[0]=bfr(oA1[0]*inv); ov[1]=bfr(oA1[1]*inv); ov[2]=bfr(oA1[2]*inv); ov[3]=bfr(oA1[3]*inv);
    *(bf16x4*)(op + 1*16) = ov;
    ov[0]=bfr(oA2[0]*inv); ov[1]=bfr(oA2[1]*inv); ov[2]=bfr(oA2[2]*inv); ov[3]=bfr(oA2[3]*inv);
    *(bf16x4*)(op + 2*16) = ov;
    ov[0]=bfr(oA3[0]*inv); ov[1]=bfr(oA3[1]*inv); ov[2]=bfr(oA3[2]*inv); ov[3]=bfr(oA3[3]*inv);
    *(bf16x4*)(op + 3*16) = ov;
  }
  if (actB) {
    float l = lB;
    l += __shfl_xor(l, 16);
    l += __shfl_xor(l, 32);
    const float inv = 1.0f / l;
    short* op = Ob + ((size_t)(b*NP) + qB)*DIM + h*HD + lg*4;
    bf16x4 ov;
    ov[0]=bfr(oB0[0]*inv); ov[1]=bfr(oB0[1]*inv); ov[2]=bfr(oB0[2]*inv); ov[3]=bfr(oB0[3]*inv);
    *(bf16x4*)(op + 0*16) = ov;
    ov[0]=bfr(oB1[0]*inv); ov[1]=bfr(oB1[1]*inv); ov[2]=bfr(oB1[2]*inv); ov[3]=bfr(oB1[3]*inv);
    *(bf16x4*)(op + 1*16) = ov;
    ov[0]=bfr(oB2[0]*inv); ov[1]=bfr(oB2[1]*inv); ov[2]=bfr(oB2[2]*inv); ov[3]=bfr(oB2[3]*inv);
    *(bf16x4*)(op + 2*16) = ov;
    ov[0]=bfr(oB3[0]*inv); ov[1]=bfr(oB3[1]*inv); ov[2]=bfr(oB3[2]*inv); ov[3]=bfr(oB3[3]*inv);
    *(bf16x4*)(op + 3*16) = ov;
  }
}

extern "C" void kernel_launch(void* const* d_in, const int* in_sizes, int n_in,
                              void* d_out, int out_size, void* d_ws, size_t ws_size,
                              hipStream_t stream) {
  const float* x_s = (const float*)d_in[0];
  const float* x_t = (const float*)d_in[1];
  const float* Wqs = (const float*)d_in[2];
  const float* Wqt = (const float*)d_in[3];
  const float* Wks = (const float*)d_in[4];
  const float* Wkt = (const float*)d_in[5];
  const float* Wvs = (const float*)d_in[6];
  const float* Wvt = (const float*)d_in[7];
  const float* rpb = (const float*)d_in[8];
  const float* pw  = (const float*)d_in[9];
  const float* pb  = (const float*)d_in[10];
  float* out = (float*)d_out;

  char* ws = (char*)d_ws;
  size_t off = 0;
  float* t_part = (float*)(ws + off); off += (size_t)3*NCHUNK*BATCH*DIM*4;
  float* t_vec  = (float*)(ws + off); off += (size_t)3*BATCH*DIM*4;
  short* Wt     = (short*)(ws + off); off += (size_t)4*DIM*DIM*2;
  short* Qb     = (short*)(ws + off); off += (size_t)MROWS*DIM*2;
  short* Ob     = (short*)(ws + off); off += (size_t)MROWS*DIM*2;
  short* Xb     = (short*)(ws + off); off += (size_t)(MROWS+256)*DIM*2;  // +256 pad rows (M-tail)
  short* Kt     = (short*)(ws + off); off += (size_t)BATCH*NH*MPAD*HD*2;
  short* Vt     = (short*)(ws + off); off += (size_t)BATCH*NH*MPAD*HD*2;
  // total ~58 MB

  prep_kernel<<<4752, 256, 0, stream>>>(x_s, x_t, Wqs, Wqt, Wks, Wkt, Wvs, Wvt, pw,
                                        Xb, Wt, t_part);
  tvec2_kernel<<<72, 256, 0, stream>>>(t_part, t_vec);
  qkv256_kernel<<<dim3(9,25), 512, 0, stream>>>(Xb, Wt, t_vec, Qb, Kt, Vt);
  attn7_kernel<<<672, 256, 0, stream>>>(Qb, Kt, Vt, rpb, Ob);
  gemm_kernel<1><<<dim3(6,49,1), 256, 0, stream>>>(Ob, Wt + (size_t)3*DIM*DIM, pb, out);
}